// Round 7
// baseline (681.474 us; speedup 1.0000x reference)
//
#include <hip/hip_runtime.h>
#include <math.h>

#define N_NODES 32768
#define N_EDGES 262144
#define EPS_C 0.24253562503633297f   // 1/sqrt(17)

// lane-broadcast: read x's value from lane g (VALU v_readlane)
__device__ __forceinline__ float rl(float v, int g) {
    return __int_as_float(__builtin_amdgcn_readlane(__float_as_int(v), g));
}

// ---------------------------------------------------------------------------
// Edge precompute: r, bessel radial basis w/ envelope, unit vectors Y1 [E,4]
// ---------------------------------------------------------------------------
__global__ __launch_bounds__(256) void edge_pre_kernel(
    const float* __restrict__ vectors, float* __restrict__ rbf, float* __restrict__ Y1)
{
    int e = blockIdx.x * 256 + threadIdx.x;
    float x = vectors[e * 3 + 0], y = vectors[e * 3 + 1], z = vectors[e * 3 + 2];
    float r2 = x * x + y * y + z * z + 1e-12f;
    float r = sqrtf(r2);
    float inv = 1.0f / r;
    *(float4*)(Y1 + e * 4) = make_float4(x * inv, y * inv, z * inv, 0.0f);
    float rc = fmaxf(r, 1e-6f);
    float r6 = r2 * r2 * r2;
    float r7 = r6 * r;
    float r8 = r6 * r2;
    float env = (r < 1.0f) ? (1.0f - 28.0f * r6 + 48.0f * r7 - 21.0f * r8) : 0.0f;
    float sc = 1.41421356237309515f * env / rc;
#pragma unroll
    for (int j = 0; j < 8; ++j)
        rbf[e * 8 + j] = sc * sinf((float)(j + 1) * 3.14159265358979323846f * rc);
}

// ---------------------------------------------------------------------------
// Node init: s = embed_s[species]  (v is never read before first write)
// ---------------------------------------------------------------------------
__global__ __launch_bounds__(256) void init_s_kernel(
    const float* __restrict__ embed_s, const int* __restrict__ species,
    float* __restrict__ s)
{
    int idx = blockIdx.x * 256 + threadIdx.x;  // over N*64
    s[idx] = embed_s[species[idx >> 6] * 64 + (idx & 63)];
}

// ---------------------------------------------------------------------------
// CSR build: histogram -> single-block scan -> scatter
// ---------------------------------------------------------------------------
__global__ __launch_bounds__(256) void hist_kernel(
    const int* __restrict__ receivers, int* __restrict__ counts)
{
    int e = blockIdx.x * 256 + threadIdx.x;
    atomicAdd(&counts[receivers[e]], 1);
}

__global__ __launch_bounds__(1024) void scan_kernel(
    const int* __restrict__ counts, int* __restrict__ row_start, int* __restrict__ cursor)
{
    __shared__ int wave_tot[16];
    int tid = threadIdx.x;
    int c[32];
    int sum = 0;
#pragma unroll
    for (int i = 0; i < 32; ++i) { c[i] = counts[tid * 32 + i]; sum += c[i]; }
    int lane = tid & 63, wv = tid >> 6;
    int x = sum;
#pragma unroll
    for (int off = 1; off < 64; off <<= 1) {
        int y = __shfl_up(x, off);
        if (lane >= off) x += y;
    }
    if (lane == 63) wave_tot[wv] = x;
    __syncthreads();
    if (wv == 0 && lane < 16) {
        int t = wave_tot[lane];
#pragma unroll
        for (int off = 1; off < 16; off <<= 1) {
            int y = __shfl_up(t, off);
            if (lane >= off) t += y;
        }
        wave_tot[lane] = t;
    }
    __syncthreads();
    int excl = x - sum + (wv ? wave_tot[wv - 1] : 0);
    int run = excl;
#pragma unroll
    for (int i = 0; i < 32; ++i) {
        row_start[tid * 32 + i] = run;
        cursor[tid * 32 + i] = run;
        run += c[i];
    }
    if (tid == 1023) row_start[32768] = run;
}

__global__ __launch_bounds__(256) void scatter_kernel(
    const int* __restrict__ receivers, int* __restrict__ cursor, int* __restrict__ edge_ids)
{
    int e = blockIdx.x * 256 + threadIdx.x;
    int slot = atomicAdd(&cursor[receivers[e]], 1);
    edge_ids[slot] = e;
}

// ---------------------------------------------------------------------------
// Gather edge kernel: wave (64 lanes = channels) owns 4 receiver nodes.
// Radial-MLP weights live in 40 VGPRs (no LDS, no barriers anywhere).
// Reads s_in/v_in, writes agg only (no atomics, no memsets).
// ---------------------------------------------------------------------------
__global__ __launch_bounds__(256) void gather_kernel(
    const float* __restrict__ rbf, const float* __restrict__ Y1,
    const int* __restrict__ senders, const int* __restrict__ edge_ids,
    const int* __restrict__ row_start,
    const float* __restrict__ s_in, const float* __restrict__ v_in,
    const float* __restrict__ Wr_i,       // [8, 320]
    float* __restrict__ agg_s, float* __restrict__ agg_v,
    int vzero)
{
    const int wid = threadIdx.x >> 6;
    const int f = threadIdx.x & 63;
    const int base = (blockIdx.x * 4 + wid) * 4;

    // register-resident radial weights: wr[p][j] = Wr[j, p*64+f]
    float wr[5][8];
#pragma unroll
    for (int j = 0; j < 8; ++j)
#pragma unroll
        for (int p = 0; p < 5; ++p)
            wr[p][j] = Wr_i[j * 320 + p * 64 + f];

    for (int t = 0; t < 4; ++t) {
        int n = base + t;
        int beg = row_start[n], end = row_start[n + 1];
        float a0 = 0.f, a1 = 0.f, a2 = 0.f, a3 = 0.f;
        int eid = (beg < end) ? edge_ids[beg] : 0;
        int snd = (beg < end) ? senders[eid] : 0;
        for (int p = beg; p < end; ++p) {
            int pn = p + 1;
            int eid_n = (pn < end) ? edge_ids[pn] : 0;
            float4 yv = *(const float4*)(Y1 + (size_t)eid * 4);
            float4 r0 = *(const float4*)(rbf + (size_t)eid * 8);
            float4 r1 = *(const float4*)(rbf + (size_t)eid * 8 + 4);
            float ss = s_in[(size_t)snd * 64 + f];
            int snd_n = (pn < end) ? senders[eid_n] : 0;

            float rb[8] = {r0.x, r0.y, r0.z, r0.w, r1.x, r1.y, r1.z, r1.w};
            float w0 = 0.f, w1 = 0.f, w2 = 0.f, w3 = 0.f, w4 = 0.f;
#pragma unroll
            for (int j = 0; j < 8; ++j) {
                w0 = fmaf(rb[j], wr[0][j], w0);
                w1 = fmaf(rb[j], wr[1][j], w1);
                w2 = fmaf(rb[j], wr[2][j], w2);
                w3 = fmaf(rb[j], wr[3][j], w3);
                w4 = fmaf(rb[j], wr[4][j], w4);
            }
            if (vzero) {
                a0 += w0 * ss;
                float ws2 = w2 * ss;
                a1 += ws2 * yv.x; a2 += ws2 * yv.y; a3 += ws2 * yv.z;
            } else {
                float vs0 = v_in[((size_t)snd * 3 + 0) * 64 + f];
                float vs1 = v_in[((size_t)snd * 3 + 1) * 64 + f];
                float vs2 = v_in[((size_t)snd * 3 + 2) * 64 + f];
                float dot = vs0 * yv.x + vs1 * yv.y + vs2 * yv.z;
                a0 += w0 * ss + w1 * dot;
                float c0 = vs1 * yv.z - vs2 * yv.y;
                float c1 = vs2 * yv.x - vs0 * yv.z;
                float c2 = vs0 * yv.y - vs1 * yv.x;
                float ws2 = w2 * ss;
                a1 += ws2 * yv.x + w3 * vs0 + w4 * c0;
                a2 += ws2 * yv.y + w3 * vs1 + w4 * c1;
                a3 += ws2 * yv.z + w3 * vs2 + w4 * c2;
            }
            eid = eid_n; snd = snd_n;
        }
        agg_s[(size_t)n * 64 + f] = a0;
        agg_v[((size_t)n * 3 + 0) * 64 + f] = a1;
        agg_v[((size_t)n * 3 + 1) * 64 + f] = a2;
        agg_v[((size_t)n * 3 + 2) * 64 + f] = a3;
    }
}

// ---------------------------------------------------------------------------
// Node kernel v3: lane = channel f, 4 waves x 4 nodes, ZERO LDS / barriers.
// All matmul x-inputs that live in read-only global memory (agg_s, agg_v,
// s_in, v_in) are wave-uniform per (node,g) -> compiler emits scalar loads;
// broadcast is free and each FMA covers all 64 channels. Only ps/pv
// (register-produced) use readlane. Weights cached in 16-VGPR chunks and
// reused across 4 nodes (and 3 k-components for Wlv/Wpv).
// Ping-pong: reads s_in/v_in, writes s_out/v_out (makes inputs provably
// un-clobbered for scalar-load promotion).
// ---------------------------------------------------------------------------
__global__ __launch_bounds__(256) void node_kernel(
    const float* __restrict__ agg_s, const float* __restrict__ agg_v,
    const float* __restrict__ s_in, const float* __restrict__ v_in,
    float* __restrict__ s_out, float* __restrict__ v_out,
    const float* __restrict__ Wls, const float* __restrict__ Wlv,
    const float* __restrict__ skip_s, const float* __restrict__ skip_v,
    const float* __restrict__ pw_i, const float* __restrict__ Wps,
    const float* __restrict__ Wpv,
    const float* __restrict__ Wread0, const float* __restrict__ Wr1a,
    const float* __restrict__ Wr1b,
    const int* __restrict__ species, float* __restrict__ out,
    int has_skip, int mode, int slot)
{
    const int wid = threadIdx.x >> 6;
    const int f = threadIdx.x & 63;
    const int base = (blockIdx.x * 4 + wid) * 4;

    int spec[4];
#pragma unroll
    for (int t = 0; t < 4; ++t) spec[t] = species[base + t];

    // ---- s2 = (agg_s @ Wls) * EPS   (x via scalar loads, w chunk-cached)
    float s2[4] = {0.f, 0.f, 0.f, 0.f};
    for (int c = 0; c < 64; c += 16) {
        float w[16];
#pragma unroll
        for (int j = 0; j < 16; ++j) w[j] = Wls[(c + j) * 64 + f];
#pragma unroll
        for (int t = 0; t < 4; ++t) {
            const float* xp = agg_s + (size_t)(base + t) * 64 + c;
#pragma unroll
            for (int j = 0; j < 16; ++j) s2[t] = fmaf(xp[j], w[j], s2[t]);
        }
    }

    // ---- v2[k] = (agg_v[k] @ Wlv) * EPS  (w reused across 12 node-dots)
    float v2[3][4];
#pragma unroll
    for (int k = 0; k < 3; ++k)
#pragma unroll
        for (int t = 0; t < 4; ++t) v2[k][t] = 0.f;
    for (int c = 0; c < 64; c += 16) {
        float w[16];
#pragma unroll
        for (int j = 0; j < 16; ++j) w[j] = Wlv[(c + j) * 64 + f];
#pragma unroll
        for (int k = 0; k < 3; ++k)
#pragma unroll
            for (int t = 0; t < 4; ++t) {
                const float* xp = agg_v + ((size_t)(base + t) * 3 + k) * 64 + c;
#pragma unroll
                for (int j = 0; j < 16; ++j) v2[k][t] = fmaf(xp[j], w[j], v2[k][t]);
            }
    }

    // ---- apply EPS, symmetric product basis (elementwise in channel)
    float ps[4], pvs[4];
#pragma unroll
    for (int t = 0; t < 4; ++t) {
        float x = s2[t] * EPS_C;
        float w0 = v2[0][t] * EPS_C, w1 = v2[1][t] * EPS_C, w2 = v2[2][t] * EPS_C;
        v2[0][t] = w0; v2[1][t] = w1; v2[2][t] = w2;
        s2[t] = x;
        const float* p = pw_i + spec[t] * 576 + f;
        float p0 = p[0], p1 = p[64], p2 = p[128], p3 = p[192], p4 = p[256];
        float p5 = p[320], p6 = p[384], p7 = p[448], p8 = p[512];
        float vv = w0 * w0 + w1 * w1 + w2 * w2;
        float x2 = x * x;
        ps[t] = p0 * x + p1 * x2 + p2 * vv + p3 * x2 * x + p4 * x * vv;
        pvs[t] = p5 + p6 * x + p7 * x2 + p8 * vv;
    }

    // ---- s_new = ps @ Wps (readlane x) + skip_s on s_in (scalar-load x)
    float s_new[4] = {0.f, 0.f, 0.f, 0.f};
    for (int c = 0; c < 64; c += 16) {
        float w[16];
#pragma unroll
        for (int j = 0; j < 16; ++j) w[j] = Wps[(c + j) * 64 + f];
#pragma unroll
        for (int t = 0; t < 4; ++t)
#pragma unroll
            for (int j = 0; j < 16; ++j)
                s_new[t] = fmaf(rl(ps[t], c + j), w[j], s_new[t]);
    }
    if (has_skip) {
#pragma unroll
        for (int t = 0; t < 4; ++t) {
            const float* Wt = skip_s + spec[t] * 4096 + f;
            const float* xp = s_in + (size_t)(base + t) * 64;
#pragma unroll 8
            for (int g = 0; g < 64; ++g)
                s_new[t] = fmaf(xp[g], Wt[g * 64], s_new[t]);
        }
    }
#pragma unroll
    for (int t = 0; t < 4; ++t) s_out[(size_t)(base + t) * 64 + f] = s_new[t];

    // ---- readout (wave-local)
    if (mode == 0) {
        float w0 = Wread0[f];
#pragma unroll
        for (int t = 0; t < 4; ++t) {
            float a = s_new[t] * w0;
            for (int off = 32; off; off >>= 1) a += __shfl_down(a, off);
            if (f == 0) out[(size_t)(base + t) * 2 + slot] = a;
        }
    } else {
        int hh = f & 15;
        int t0 = f >> 4;             // 4 nodes x 16 hidden = 64 lanes exactly
        float a[4] = {0.f, 0.f, 0.f, 0.f};
        for (int g = 0; g < 64; ++g) {
            float wa = Wr1a[g * 16 + hh];
            a[0] = fmaf(rl(s_new[0], g), wa, a[0]);
            a[1] = fmaf(rl(s_new[1], g), wa, a[1]);
            a[2] = fmaf(rl(s_new[2], g), wa, a[2]);
            a[3] = fmaf(rl(s_new[3], g), wa, a[3]);
        }
        float av = (t0 == 0) ? a[0] : (t0 == 1) ? a[1] : (t0 == 2) ? a[2] : a[3];
        float r0 = (av / (1.f + expf(-av))) * Wr1b[hh];
        for (int off = 8; off; off >>= 1) r0 += __shfl_down(r0, off);
        if (hh == 0) out[(size_t)(base + t0) * 2 + slot] = r0;
    }

    // ---- v_new[k] = (pvs*v2[k]) @ Wpv (readlane x) + skip_v on v_in
    for (int k = 0; k < 3; ++k) {
        float pv[4];
#pragma unroll
        for (int t = 0; t < 4; ++t) pv[t] = pvs[t] * v2[k][t];
        float acc[4] = {0.f, 0.f, 0.f, 0.f};
        for (int c = 0; c < 64; c += 16) {
            float w[16];
#pragma unroll
            for (int j = 0; j < 16; ++j) w[j] = Wpv[(c + j) * 64 + f];
#pragma unroll
            for (int t = 0; t < 4; ++t)
#pragma unroll
                for (int j = 0; j < 16; ++j)
                    acc[t] = fmaf(rl(pv[t], c + j), w[j], acc[t]);
        }
        if (has_skip) {
#pragma unroll
            for (int t = 0; t < 4; ++t) {
                const float* Wt = skip_v + spec[t] * 4096 + f;
                const float* xp = v_in + ((size_t)(base + t) * 3 + k) * 64;
#pragma unroll 8
                for (int g = 0; g < 64; ++g)
                    acc[t] = fmaf(xp[g], Wt[g * 64], acc[t]);
            }
        }
#pragma unroll
        for (int t = 0; t < 4; ++t)
            v_out[((size_t)(base + t) * 3 + k) * 64 + f] = acc[t];
    }
}

// ---------------------------------------------------------------------------
extern "C" void kernel_launch(void* const* d_in, const int* in_sizes, int n_in,
                              void* d_out, int out_size, void* d_ws, size_t ws_size,
                              hipStream_t stream)
{
    const float* vectors = (const float*)d_in[0];
    const float* embed_s = (const float*)d_in[1];
    const float* Wr      = (const float*)d_in[2];   // [2,8,320]
    const float* Wls     = (const float*)d_in[3];   // [2,64,64]
    const float* Wlv     = (const float*)d_in[4];
    const float* skip_s  = (const float*)d_in[5];   // [10,64,64]
    const float* skip_v  = (const float*)d_in[6];
    const float* pw      = (const float*)d_in[7];   // [2,10,9,64]
    const float* Wps     = (const float*)d_in[8];
    const float* Wpv     = (const float*)d_in[9];
    const float* Wread0  = (const float*)d_in[10];  // [64,1]
    const float* Wr1a    = (const float*)d_in[11];  // [64,16]
    const float* Wr1b    = (const float*)d_in[12];  // [16,1]
    const int* senders   = (const int*)d_in[13];
    const int* receivers = (const int*)d_in[14];
    const int* species   = (const int*)d_in[15];
    float* out = (float*)d_out;

    // workspace layout (floats / ints); ping-pong sA/vA <-> sB/vB
    float* ws = (float*)d_ws;
    float* rbf   = ws; ws += (size_t)N_EDGES * 8;   // 8 MB
    float* Y1    = ws; ws += (size_t)N_EDGES * 4;   // 4 MB (padded)
    float* sA    = ws; ws += (size_t)N_NODES * 64;  // 8 MB
    float* vA    = ws; ws += (size_t)N_NODES * 192; // 24 MB  [N,3,64]
    float* sB    = ws; ws += (size_t)N_NODES * 64;  // 8 MB
    float* vB    = ws; ws += (size_t)N_NODES * 192; // 24 MB
    float* agg_s = ws; ws += (size_t)N_NODES * 64;  // 8 MB
    float* agg_v = ws; ws += (size_t)N_NODES * 192; // 24 MB
    int* counts    = (int*)ws; ws += N_NODES;       // 128 KB
    int* row_start = (int*)ws; ws += N_NODES + 4;
    int* cursor    = (int*)ws; ws += N_NODES;
    int* edge_ids  = (int*)ws; ws += N_EDGES;       // 1 MB

    edge_pre_kernel<<<N_EDGES / 256, 256, 0, stream>>>(vectors, rbf, Y1);
    init_s_kernel<<<N_NODES * 64 / 256, 256, 0, stream>>>(embed_s, species, sA);

    // CSR build (once; reused by both interactions)
    hipMemsetAsync(counts, 0, N_NODES * sizeof(int), stream);
    hist_kernel<<<N_EDGES / 256, 256, 0, stream>>>(receivers, counts);
    scan_kernel<<<1, 1024, 0, stream>>>(counts, row_start, cursor);
    scatter_kernel<<<N_EDGES / 256, 256, 0, stream>>>(receivers, cursor, edge_ids);

    // interaction 0: gather from sA (v unused), node writes sB/vB
    gather_kernel<<<N_NODES / 16, 256, 0, stream>>>(
        rbf, Y1, senders, edge_ids, row_start, sA, vA, Wr, agg_s, agg_v, 1);
    node_kernel<<<N_NODES / 16, 256, 0, stream>>>(
        agg_s, agg_v, sA, vA, sB, vB,
        Wls, Wlv, skip_s, skip_v, pw, Wps, Wpv,
        Wread0, Wr1a, Wr1b, species, out, 0, 0, 0);

    // interaction 1: gather from sB/vB, node reads sB/vB, writes sA/vA
    gather_kernel<<<N_NODES / 16, 256, 0, stream>>>(
        rbf, Y1, senders, edge_ids, row_start, sB, vB, Wr + 2560, agg_s, agg_v, 0);
    node_kernel<<<N_NODES / 16, 256, 0, stream>>>(
        agg_s, agg_v, sB, vB, sA, vA,
        Wls + 4096, Wlv + 4096, skip_s, skip_v,
        pw + 5760, Wps + 4096, Wpv + 4096,
        Wread0, Wr1a, Wr1b, species, out, 1, 1, 1);
}

// Round 8
// 591.741 us; speedup vs baseline: 1.1516x; 1.1516x over previous
//
#include <hip/hip_runtime.h>
#include <hip/hip_bf16.h>
#include <math.h>

#define N_NODES 32768
#define N_EDGES 262144
#define EPS_C 0.24253562503633297f   // 1/sqrt(17)
#define NSPEC 10

typedef __attribute__((ext_vector_type(8))) short short8;   // 8 bf16
typedef __attribute__((ext_vector_type(4))) float f32x4;    // 4 fp32 acc

#define MFMA16(a, b, c) __builtin_amdgcn_mfma_f32_16x16x32_bf16(a, b, c, 0, 0, 0)

__device__ __forceinline__ short2 cvt2(float a, float b) {
    union { __hip_bfloat162 h; short2 s; } u;
    u.h = __float22bfloat162_rn(make_float2(a, b));
    return u.s;
}
__device__ __forceinline__ short8 cvt8(float4 a, float4 b) {
    short2 p0 = cvt2(a.x, a.y), p1 = cvt2(a.z, a.w);
    short2 p2 = cvt2(b.x, b.y), p3 = cvt2(b.z, b.w);
    short8 r;
    r[0] = p0.x; r[1] = p0.y; r[2] = p1.x; r[3] = p1.y;
    r[4] = p2.x; r[5] = p2.y; r[6] = p3.x; r[7] = p3.y;
    return r;
}
// A-fragment (k-half h) from an fp32 row: elements row[h*32 + q*8 + 0..7]
__device__ __forceinline__ short8 loadArow(const float* rowp, int h, int q) {
    const float* p = rowp + h * 32 + q * 8;
    return cvt8(*(const float4*)p, *(const float4*)(p + 4));
}
// B-fragment from packed bf16 weights (layout built by pack_kernel)
__device__ __forceinline__ short8 loadB(const short* P, int t, int h, int l) {
    return *(const short8*)(P + (((t * 2 + h) * 64 + l) << 3));
}

// ---------------------------------------------------------------------------
// Edge precompute: bessel radial basis w/ envelope, unit vectors Y1 [E,4]
// ---------------------------------------------------------------------------
__global__ __launch_bounds__(256) void edge_pre_kernel(
    const float* __restrict__ vectors, float* __restrict__ rbf, float* __restrict__ Y1)
{
    int e = blockIdx.x * 256 + threadIdx.x;
    float x = vectors[e * 3 + 0], y = vectors[e * 3 + 1], z = vectors[e * 3 + 2];
    float r2 = x * x + y * y + z * z + 1e-12f;
    float r = sqrtf(r2);
    float inv = 1.0f / r;
    *(float4*)(Y1 + e * 4) = make_float4(x * inv, y * inv, z * inv, 0.0f);
    float rc = fmaxf(r, 1e-6f);
    float r6 = r2 * r2 * r2;
    float r7 = r6 * r;
    float r8 = r6 * r2;
    float env = (r < 1.0f) ? (1.0f - 28.0f * r6 + 48.0f * r7 - 21.0f * r8) : 0.0f;
    float sc = 1.41421356237309515f * env / rc;
#pragma unroll
    for (int j = 0; j < 8; ++j)
        rbf[e * 8 + j] = sc * sinf((float)(j + 1) * 3.14159265358979323846f * rc);
}

// ---------------------------------------------------------------------------
// Species sort: histogram -> serial scan (10 bins) -> scatter (sidx/rank)
// ---------------------------------------------------------------------------
__global__ __launch_bounds__(256) void hist_spec_kernel(
    const int* __restrict__ species, int* __restrict__ counts_z)
{
    int n = blockIdx.x * 256 + threadIdx.x;
    atomicAdd(&counts_z[species[n]], 1);
}
__global__ __launch_bounds__(64) void scan_spec_kernel(
    const int* __restrict__ counts_z, int* __restrict__ cursor_z)
{
    if (threadIdx.x == 0) {
        int run = 0;
        for (int z = 0; z < NSPEC; ++z) { cursor_z[z] = run; run += counts_z[z]; }
    }
}
__global__ __launch_bounds__(256) void scatter_spec_kernel(
    const int* __restrict__ species, int* __restrict__ cursor_z,
    int* __restrict__ sidx, int* __restrict__ rank, int* __restrict__ spec_srt)
{
    int n = blockIdx.x * 256 + threadIdx.x;
    int sp = species[n];
    int slot = atomicAdd(&cursor_z[sp], 1);
    sidx[slot] = n;
    rank[n] = slot;
    spec_srt[slot] = sp;
}

// ---------------------------------------------------------------------------
// Receiver CSR build (original node ids): histogram -> scan -> scatter
// ---------------------------------------------------------------------------
__global__ __launch_bounds__(256) void hist_kernel(
    const int* __restrict__ receivers, int* __restrict__ counts)
{
    int e = blockIdx.x * 256 + threadIdx.x;
    atomicAdd(&counts[receivers[e]], 1);
}

__global__ __launch_bounds__(1024) void scan_kernel(
    const int* __restrict__ counts, int* __restrict__ row_start, int* __restrict__ cursor)
{
    __shared__ int wave_tot[16];
    int tid = threadIdx.x;
    int c[32];
    int sum = 0;
#pragma unroll
    for (int i = 0; i < 32; ++i) { c[i] = counts[tid * 32 + i]; sum += c[i]; }
    int lane = tid & 63, wv = tid >> 6;
    int x = sum;
#pragma unroll
    for (int off = 1; off < 64; off <<= 1) {
        int y = __shfl_up(x, off);
        if (lane >= off) x += y;
    }
    if (lane == 63) wave_tot[wv] = x;
    __syncthreads();
    if (wv == 0 && lane < 16) {
        int t = wave_tot[lane];
#pragma unroll
        for (int off = 1; off < 16; off <<= 1) {
            int y = __shfl_up(t, off);
            if (lane >= off) t += y;
        }
        wave_tot[lane] = t;
    }
    __syncthreads();
    int excl = x - sum + (wv ? wave_tot[wv - 1] : 0);
    int run = excl;
#pragma unroll
    for (int i = 0; i < 32; ++i) {
        row_start[tid * 32 + i] = run;
        cursor[tid * 32 + i] = run;
        run += c[i];
    }
    if (tid == 1023) row_start[32768] = run;
}

__global__ __launch_bounds__(256) void scatter_kernel(
    const int* __restrict__ receivers, int* __restrict__ cursor, int* __restrict__ edge_ids)
{
    int e = blockIdx.x * 256 + threadIdx.x;
    int slot = atomicAdd(&cursor[receivers[e]], 1);
    edge_ids[slot] = e;
}

// ranked senders per CSR slot (sorted-space index into s/v)
__global__ __launch_bounds__(256) void sr_kernel(
    const int* __restrict__ senders, const int* __restrict__ edge_ids,
    const int* __restrict__ rank, int* __restrict__ senders_r)
{
    int p = blockIdx.x * 256 + threadIdx.x;
    senders_r[p] = rank[senders[edge_ids[p]]];
}

// ---------------------------------------------------------------------------
// Node init (sorted layout): s[i] = embed_s[spec_srt[i]]
// ---------------------------------------------------------------------------
__global__ __launch_bounds__(256) void init_s_kernel(
    const float* __restrict__ embed_s, const int* __restrict__ spec_srt,
    float* __restrict__ s)
{
    int idx = blockIdx.x * 256 + threadIdx.x;
    s[idx] = embed_s[spec_srt[idx >> 6] * 64 + (idx & 63)];
}

// ---------------------------------------------------------------------------
// Weight pre-pack: 28 64x64 fp32 matrices -> bf16 B-fragment order.
// Matrix m: 0/1 Wls(i), 2/3 Wlv(i), 4/5 Wps(i), 6/7 Wpv(i), 8..17 skip_s[z],
// 18..27 skip_v[z]. Frag elem: B[k=h*32+(l>>4)*8+j][n=t*16+(l&15)],
// packed at ((t*2+h)*64+l)*8 + j.
// ---------------------------------------------------------------------------
__global__ __launch_bounds__(256) void pack_kernel(
    const float* __restrict__ Wls, const float* __restrict__ Wlv,
    const float* __restrict__ Wps, const float* __restrict__ Wpv,
    const float* __restrict__ skip_s, const float* __restrict__ skip_v,
    short* __restrict__ packW)
{
    int idx = blockIdx.x * 256 + threadIdx.x;   // 28*4096 = 114688
    if (idx >= 28 * 4096) return;
    int m = idx >> 12, e = idx & 4095;
    int t = e >> 10, h = (e >> 9) & 1, l = (e >> 3) & 63, j = e & 7;
    int fi = h * 32 + ((l >> 4) << 3) + j;
    int fo = t * 16 + (l & 15);
    const float* src;
    if      (m < 2)  src = Wls    + m * 4096;
    else if (m < 4)  src = Wlv    + (m - 2) * 4096;
    else if (m < 6)  src = Wps    + (m - 4) * 4096;
    else if (m < 8)  src = Wpv    + (m - 6) * 4096;
    else if (m < 18) src = skip_s + (m - 8) * 4096;
    else             src = skip_v + (m - 18) * 4096;
    packW[idx] = cvt2(src[fi * 64 + fo], 0.f).x;
}

// ---------------------------------------------------------------------------
// Gather edge kernel (sorted rows): wave owns 4 sorted positions; reads
// ranked senders directly (no eid->snd chain); writes agg at sorted position.
// Radial weights in 40 VGPRs; no LDS, no atomics, no barriers.
// ---------------------------------------------------------------------------
__global__ __launch_bounds__(256) void gather_kernel(
    const float* __restrict__ rbf, const float* __restrict__ Y1,
    const int* __restrict__ edge_ids, const int* __restrict__ senders_r,
    const int* __restrict__ row_start, const int* __restrict__ sidx,
    const float* __restrict__ s_in, const float* __restrict__ v_in,
    const float* __restrict__ Wr_i,
    float* __restrict__ agg_s, float* __restrict__ agg_v,
    int vzero)
{
    const int wid = threadIdx.x >> 6;
    const int f = threadIdx.x & 63;
    const int base = (blockIdx.x * 4 + wid) * 4;

    float wr[5][8];
#pragma unroll
    for (int j = 0; j < 8; ++j)
#pragma unroll
        for (int p = 0; p < 5; ++p)
            wr[p][j] = Wr_i[j * 320 + p * 64 + f];

    for (int t = 0; t < 4; ++t) {
        int i = base + t;
        int n = sidx[i];
        int beg = row_start[n], end = row_start[n + 1];
        float a0 = 0.f, a1 = 0.f, a2 = 0.f, a3 = 0.f;
        int eid = (beg < end) ? edge_ids[beg] : 0;
        int sr  = (beg < end) ? senders_r[beg] : 0;
        for (int p = beg; p < end; ++p) {
            int pn = p + 1;
            int eid_n = (pn < end) ? edge_ids[pn] : 0;
            int sr_n  = (pn < end) ? senders_r[pn] : 0;
            float4 yv = *(const float4*)(Y1 + (size_t)eid * 4);
            float4 r0 = *(const float4*)(rbf + (size_t)eid * 8);
            float4 r1 = *(const float4*)(rbf + (size_t)eid * 8 + 4);
            float ss = s_in[(size_t)sr * 64 + f];

            float rb[8] = {r0.x, r0.y, r0.z, r0.w, r1.x, r1.y, r1.z, r1.w};
            float w0 = 0.f, w1 = 0.f, w2 = 0.f, w3 = 0.f, w4 = 0.f;
#pragma unroll
            for (int j = 0; j < 8; ++j) {
                w0 = fmaf(rb[j], wr[0][j], w0);
                w1 = fmaf(rb[j], wr[1][j], w1);
                w2 = fmaf(rb[j], wr[2][j], w2);
                w3 = fmaf(rb[j], wr[3][j], w3);
                w4 = fmaf(rb[j], wr[4][j], w4);
            }
            if (vzero) {
                a0 += w0 * ss;
                float ws2 = w2 * ss;
                a1 += ws2 * yv.x; a2 += ws2 * yv.y; a3 += ws2 * yv.z;
            } else {
                float vs0 = v_in[((size_t)sr * 3 + 0) * 64 + f];
                float vs1 = v_in[((size_t)sr * 3 + 1) * 64 + f];
                float vs2 = v_in[((size_t)sr * 3 + 2) * 64 + f];
                float dot = vs0 * yv.x + vs1 * yv.y + vs2 * yv.z;
                a0 += w0 * ss + w1 * dot;
                float c0 = vs1 * yv.z - vs2 * yv.y;
                float c1 = vs2 * yv.x - vs0 * yv.z;
                float c2 = vs0 * yv.y - vs1 * yv.x;
                float ws2 = w2 * ss;
                a1 += ws2 * yv.x + w3 * vs0 + w4 * c0;
                a2 += ws2 * yv.y + w3 * vs1 + w4 * c1;
                a3 += ws2 * yv.z + w3 * vs2 + w4 * c2;
            }
            eid = eid_n; sr = sr_n;
        }
        agg_s[(size_t)i * 64 + f] = a0;
        agg_v[((size_t)i * 3 + 0) * 64 + f] = a1;
        agg_v[((size_t)i * 3 + 1) * 64 + f] = a2;
        agg_v[((size_t)i * 3 + 2) * 64 + f] = a3;
    }
}

// ---------------------------------------------------------------------------
// MFMA node kernel: wave = 16 sorted nodes (species-uniform in all but
// segment-boundary tiles). All 12 GEMMs on mfma_f32_16x16x32_bf16.
// A layout: m=lane&15, k=(lane>>4)*8+j.  D: row=(lane>>4)*4+reg, col=lane&15.
// ps/pv D->A transposes via wave-private LDS, stride 65 (bank-clean b32).
// s/v updated in-place (each wave touches only its own rows).
// ---------------------------------------------------------------------------
__global__ __launch_bounds__(256) void node_mfma_kernel(
    const float* __restrict__ agg_s, const float* __restrict__ agg_v,
    float* s, float* v,
    const short* __restrict__ packW, int it,
    const float* __restrict__ pw_i,
    const int* __restrict__ spec_srt,
    int has_skip)
{
    const int l = threadIdx.x & 63;
    const int wid = threadIdx.x >> 6;
    const int cl = l & 15;
    const int q = l >> 4;
    const int i16 = (blockIdx.x * 4 + wid) * 16;
    __shared__ float xls_all[4][16 * 65];
    float* xls = xls_all[wid];

    const short* pWls = packW + (size_t)(0 + it) * 4096;
    const short* pWlv = packW + (size_t)(2 + it) * 4096;
    const short* pWps = packW + (size_t)(4 + it) * 4096;
    const short* pWpv = packW + (size_t)(6 + it) * 4096;
    const short* pSkS = packW + (size_t)8 * 4096;
    const short* pSkV = packW + (size_t)18 * 4096;
    const short8 z8 = {0, 0, 0, 0, 0, 0, 0, 0};

    // ---- A fragments for agg
    const float* ars = agg_s + (size_t)(i16 + cl) * 64;
    short8 As[2] = { loadArow(ars, 0, q), loadArow(ars, 1, q) };
    short8 Av[3][2];
#pragma unroll
    for (int k = 0; k < 3; ++k) {
        const float* r = agg_v + ((size_t)(i16 + cl) * 3 + k) * 64;
        Av[k][0] = loadArow(r, 0, q);
        Av[k][1] = loadArow(r, 1, q);
    }

    // ---- s2 = agg_s @ Wls
    f32x4 sD[4];
#pragma unroll
    for (int t = 0; t < 4; ++t) {
        f32x4 acc = {0.f, 0.f, 0.f, 0.f};
        acc = MFMA16(As[0], loadB(pWls, t, 0, l), acc);
        acc = MFMA16(As[1], loadB(pWls, t, 1, l), acc);
        sD[t] = acc;
    }

    // ---- v2[k] = agg_v[k] @ Wlv  (B reused across k)
    f32x4 vD[3][4];
#pragma unroll
    for (int k = 0; k < 3; ++k)
#pragma unroll
        for (int t = 0; t < 4; ++t) vD[k][t] = (f32x4){0.f, 0.f, 0.f, 0.f};
#pragma unroll
    for (int t = 0; t < 4; ++t)
#pragma unroll
        for (int h = 0; h < 2; ++h) {
            short8 b = loadB(pWlv, t, h, l);
#pragma unroll
            for (int k = 0; k < 3; ++k) vD[k][t] = MFMA16(Av[k][h], b, vD[k][t]);
        }

    // ---- symmetric product basis in D-layout (node m=q*4+r, ch fo=t*16+cl)
    int z0 = spec_srt[i16], z1 = spec_srt[i16 + 15];
    float psD[4][4], pvsD[4][4];
    if (z0 == z1) {
        const float* pb = pw_i + z0 * 576 + cl;
        float pc[9][4];
#pragma unroll
        for (int c = 0; c < 9; ++c)
#pragma unroll
            for (int t = 0; t < 4; ++t) pc[c][t] = pb[c * 64 + t * 16];
#pragma unroll
        for (int t = 0; t < 4; ++t)
#pragma unroll
            for (int r = 0; r < 4; ++r) {
                float x = sD[t][r] * EPS_C;
                float w0 = vD[0][t][r] * EPS_C;
                float w1 = vD[1][t][r] * EPS_C;
                float w2 = vD[2][t][r] * EPS_C;
                vD[0][t][r] = w0; vD[1][t][r] = w1; vD[2][t][r] = w2;
                float vv = w0 * w0 + w1 * w1 + w2 * w2;
                float x2 = x * x;
                psD[t][r] = pc[0][t] * x + pc[1][t] * x2 + pc[2][t] * vv
                          + pc[3][t] * x2 * x + pc[4][t] * x * vv;
                pvsD[t][r] = pc[5][t] + pc[6][t] * x + pc[7][t] * x2 + pc[8][t] * vv;
            }
    } else {
#pragma unroll
        for (int r = 0; r < 4; ++r) {
            int z = spec_srt[i16 + q * 4 + r];
            const float* pb = pw_i + z * 576 + cl;
#pragma unroll
            for (int t = 0; t < 4; ++t) {
                float p0 = pb[t*16], p1 = pb[64+t*16], p2 = pb[128+t*16];
                float p3 = pb[192+t*16], p4 = pb[256+t*16], p5 = pb[320+t*16];
                float p6 = pb[384+t*16], p7 = pb[448+t*16], p8 = pb[512+t*16];
                float x = sD[t][r] * EPS_C;
                float w0 = vD[0][t][r] * EPS_C;
                float w1 = vD[1][t][r] * EPS_C;
                float w2 = vD[2][t][r] * EPS_C;
                vD[0][t][r] = w0; vD[1][t][r] = w1; vD[2][t][r] = w2;
                float vv = w0 * w0 + w1 * w1 + w2 * w2;
                float x2 = x * x;
                psD[t][r] = p0 * x + p1 * x2 + p2 * vv + p3 * x2 * x + p4 * x * vv;
                pvsD[t][r] = p5 + p6 * x + p7 * x2 + p8 * vv;
            }
        }
    }

    // ---- transpose ps (D -> A) via LDS
#pragma unroll
    for (int t = 0; t < 4; ++t)
#pragma unroll
        for (int r = 0; r < 4; ++r)
            xls[(q * 4 + r) * 65 + t * 16 + cl] = psD[t][r];
    short8 psA[2];
#pragma unroll
    for (int h = 0; h < 2; ++h) {
        const float* rp = xls + cl * 65 + h * 32 + q * 8;
        float t0 = rp[0], t1 = rp[1], t2 = rp[2], t3 = rp[3];
        float t4 = rp[4], t5 = rp[5], t6 = rp[6], t7 = rp[7];
        psA[h] = cvt8(make_float4(t0, t1, t2, t3), make_float4(t4, t5, t6, t7));
    }

    // ---- s_new = ps @ Wps (+ per-species skip on pre-interaction s)
    f32x4 snD[4];
#pragma unroll
    for (int t = 0; t < 4; ++t) {
        f32x4 acc = {0.f, 0.f, 0.f, 0.f};
        acc = MFMA16(psA[0], loadB(pWps, t, 0, l), acc);
        acc = MFMA16(psA[1], loadB(pWps, t, 1, l), acc);
        snD[t] = acc;
    }
    if (has_skip) {
        const float* srow = s + (size_t)(i16 + cl) * 64;
        short8 Ai0 = loadArow(srow, 0, q), Ai1 = loadArow(srow, 1, q);
        int myz = spec_srt[i16 + cl];
        for (int z = z0; z <= z1; ++z) {
            bool keep = (myz == z);
            short8 m0 = keep ? Ai0 : z8;
            short8 m1 = keep ? Ai1 : z8;
            const short* pz = pSkS + (size_t)z * 4096;
#pragma unroll
            for (int t = 0; t < 4; ++t) {
                snD[t] = MFMA16(m0, loadB(pz, t, 0, l), snD[t]);
                snD[t] = MFMA16(m1, loadB(pz, t, 1, l), snD[t]);
            }
        }
    }
#pragma unroll
    for (int t = 0; t < 4; ++t)
#pragma unroll
        for (int r = 0; r < 4; ++r)
            s[(size_t)(i16 + q * 4 + r) * 64 + t * 16 + cl] = snD[t][r];

    // ---- pv[k] = pvs * v2[k]: transpose each k (D -> A)
    short8 pvA[3][2];
#pragma unroll
    for (int k = 0; k < 3; ++k) {
#pragma unroll
        for (int t = 0; t < 4; ++t)
#pragma unroll
            for (int r = 0; r < 4; ++r)
                xls[(q * 4 + r) * 65 + t * 16 + cl] = pvsD[t][r] * vD[k][t][r];
#pragma unroll
        for (int h = 0; h < 2; ++h) {
            const float* rp = xls + cl * 65 + h * 32 + q * 8;
            float t0 = rp[0], t1 = rp[1], t2 = rp[2], t3 = rp[3];
            float t4 = rp[4], t5 = rp[5], t6 = rp[6], t7 = rp[7];
            pvA[k][h] = cvt8(make_float4(t0, t1, t2, t3), make_float4(t4, t5, t6, t7));
        }
    }

    // ---- v_new[k] = pv[k] @ Wpv (+ per-species skip on pre-interaction v)
    f32x4 vnD[3][4];
#pragma unroll
    for (int k = 0; k < 3; ++k)
#pragma unroll
        for (int t = 0; t < 4; ++t) vnD[k][t] = (f32x4){0.f, 0.f, 0.f, 0.f};
#pragma unroll
    for (int t = 0; t < 4; ++t)
#pragma unroll
        for (int h = 0; h < 2; ++h) {
            short8 b = loadB(pWpv, t, h, l);
#pragma unroll
            for (int k = 0; k < 3; ++k) vnD[k][t] = MFMA16(pvA[k][h], b, vnD[k][t]);
        }
    if (has_skip) {
        short8 Aiv[3][2];
#pragma unroll
        for (int k = 0; k < 3; ++k) {
            const float* r = v + ((size_t)(i16 + cl) * 3 + k) * 64;
            Aiv[k][0] = loadArow(r, 0, q);
            Aiv[k][1] = loadArow(r, 1, q);
        }
        int myz = spec_srt[i16 + cl];
        for (int z = z0; z <= z1; ++z) {
            bool keep = (myz == z);
            const short* pz = pSkV + (size_t)z * 4096;
#pragma unroll
            for (int t = 0; t < 4; ++t)
#pragma unroll
                for (int h = 0; h < 2; ++h) {
                    short8 b = loadB(pz, t, h, l);
#pragma unroll
                    for (int k = 0; k < 3; ++k) {
                        short8 a = keep ? Aiv[k][h] : z8;
                        vnD[k][t] = MFMA16(a, b, vnD[k][t]);
                    }
                }
        }
    }
#pragma unroll
    for (int k = 0; k < 3; ++k)
#pragma unroll
        for (int t = 0; t < 4; ++t)
#pragma unroll
            for (int r = 0; r < 4; ++r)
                v[((size_t)(i16 + q * 4 + r) * 3 + k) * 64 + t * 16 + cl] = vnD[k][t][r];
}

// ---------------------------------------------------------------------------
// Readouts (sorted s -> out[sidx])
// ---------------------------------------------------------------------------
__global__ __launch_bounds__(256) void read0_kernel(
    const float* __restrict__ s, const float* __restrict__ Wread0,
    const int* __restrict__ sidx, float* __restrict__ out)
{
    const int wid = threadIdx.x >> 6;
    const int f = threadIdx.x & 63;
    const int i4 = (blockIdx.x * 4 + wid) * 4;
    float w0 = Wread0[f];
#pragma unroll
    for (int t = 0; t < 4; ++t) {
        float a = s[(size_t)(i4 + t) * 64 + f] * w0;
        for (int off = 32; off; off >>= 1) a += __shfl_down(a, off);
        if (f == 0) out[(size_t)sidx[i4 + t] * 2 + 0] = a;
    }
}

__global__ __launch_bounds__(256) void read1_kernel(
    const float* __restrict__ s, const float* __restrict__ Wr1a,
    const float* __restrict__ Wr1b, const int* __restrict__ sidx,
    float* __restrict__ out)
{
    const int wid = threadIdx.x >> 6;
    const int f = threadIdx.x & 63;
    const int i4 = (blockIdx.x * 4 + wid) * 4;
    int hh = f & 15;
    int t0 = f >> 4;
    float a = 0.f;
    const float* sp = s + (size_t)(i4 + t0) * 64;
#pragma unroll 8
    for (int g = 0; g < 64; ++g)
        a = fmaf(sp[g], Wr1a[g * 16 + hh], a);
    float r0 = (a / (1.f + expf(-a))) * Wr1b[hh];
    for (int off = 8; off; off >>= 1) r0 += __shfl_down(r0, off);
    if (hh == 0) out[(size_t)sidx[i4 + t0] * 2 + 1] = r0;
}

// ---------------------------------------------------------------------------
extern "C" void kernel_launch(void* const* d_in, const int* in_sizes, int n_in,
                              void* d_out, int out_size, void* d_ws, size_t ws_size,
                              hipStream_t stream)
{
    const float* vectors = (const float*)d_in[0];
    const float* embed_s = (const float*)d_in[1];
    const float* Wr      = (const float*)d_in[2];   // [2,8,320]
    const float* Wls     = (const float*)d_in[3];   // [2,64,64]
    const float* Wlv     = (const float*)d_in[4];
    const float* skip_s  = (const float*)d_in[5];   // [10,64,64]
    const float* skip_v  = (const float*)d_in[6];
    const float* pw      = (const float*)d_in[7];   // [2,10,9,64]
    const float* Wps     = (const float*)d_in[8];
    const float* Wpv     = (const float*)d_in[9];
    const float* Wread0  = (const float*)d_in[10];  // [64,1]
    const float* Wr1a    = (const float*)d_in[11];  // [64,16]
    const float* Wr1b    = (const float*)d_in[12];  // [16,1]
    const int* senders   = (const int*)d_in[13];
    const int* receivers = (const int*)d_in[14];
    const int* species   = (const int*)d_in[15];
    float* out = (float*)d_out;

    // workspace (all sorted-node layout for s/v/agg)
    float* ws = (float*)d_ws;
    float* rbf   = ws; ws += (size_t)N_EDGES * 8;   // 8 MB
    float* Y1    = ws; ws += (size_t)N_EDGES * 4;   // 4 MB
    float* s     = ws; ws += (size_t)N_NODES * 64;  // 8 MB
    float* v     = ws; ws += (size_t)N_NODES * 192; // 24 MB
    float* agg_s = ws; ws += (size_t)N_NODES * 64;  // 8 MB
    float* agg_v = ws; ws += (size_t)N_NODES * 192; // 24 MB
    int* counts    = (int*)ws; ws += N_NODES;
    int* row_start = (int*)ws; ws += N_NODES + 4;
    int* cursor    = (int*)ws; ws += N_NODES;
    int* edge_ids  = (int*)ws; ws += N_EDGES;
    int* senders_r = (int*)ws; ws += N_EDGES;
    int* sidx      = (int*)ws; ws += N_NODES;
    int* rank      = (int*)ws; ws += N_NODES;
    int* spec_srt  = (int*)ws; ws += N_NODES;
    int* counts_z  = (int*)ws; ws += 64;
    int* cursor_z  = (int*)ws; ws += 64;
    short* packW   = (short*)ws;                    // 28*4096 bf16 = 224 KB

    edge_pre_kernel<<<N_EDGES / 256, 256, 0, stream>>>(vectors, rbf, Y1);

    // species sort
    hipMemsetAsync(counts_z, 0, 64 * sizeof(int), stream);
    hist_spec_kernel<<<N_NODES / 256, 256, 0, stream>>>(species, counts_z);
    scan_spec_kernel<<<1, 64, 0, stream>>>(counts_z, cursor_z);
    scatter_spec_kernel<<<N_NODES / 256, 256, 0, stream>>>(
        species, cursor_z, sidx, rank, spec_srt);

    // receiver CSR + ranked senders
    hipMemsetAsync(counts, 0, N_NODES * sizeof(int), stream);
    hist_kernel<<<N_EDGES / 256, 256, 0, stream>>>(receivers, counts);
    scan_kernel<<<1, 1024, 0, stream>>>(counts, row_start, cursor);
    scatter_kernel<<<N_EDGES / 256, 256, 0, stream>>>(receivers, cursor, edge_ids);
    sr_kernel<<<N_EDGES / 256, 256, 0, stream>>>(senders, edge_ids, rank, senders_r);

    init_s_kernel<<<N_NODES * 64 / 256, 256, 0, stream>>>(embed_s, spec_srt, s);
    pack_kernel<<<448, 256, 0, stream>>>(Wls, Wlv, Wps, Wpv, skip_s, skip_v, packW);

    // interaction 0
    gather_kernel<<<N_NODES / 16, 256, 0, stream>>>(
        rbf, Y1, edge_ids, senders_r, row_start, sidx, s, v, Wr, agg_s, agg_v, 1);
    node_mfma_kernel<<<N_NODES / 64, 256, 0, stream>>>(
        agg_s, agg_v, s, v, packW, 0, pw, spec_srt, 0);
    read0_kernel<<<N_NODES / 16, 256, 0, stream>>>(s, Wread0, sidx, out);

    // interaction 1
    gather_kernel<<<N_NODES / 16, 256, 0, stream>>>(
        rbf, Y1, edge_ids, senders_r, row_start, sidx, s, v, Wr + 2560, agg_s, agg_v, 0);
    node_mfma_kernel<<<N_NODES / 64, 256, 0, stream>>>(
        agg_s, agg_v, s, v, packW, 1, pw + 5760, spec_srt, 1);
    read1_kernel<<<N_NODES / 16, 256, 0, stream>>>(s, Wr1a, Wr1b, sidx, out);
}

// Round 9
// 346.450 us; speedup vs baseline: 1.9670x; 1.7080x over previous
//
#include <hip/hip_runtime.h>
#include <hip/hip_bf16.h>
#include <math.h>

#define N_NODES 32768
#define N_EDGES 262144
#define EPS_C 0.24253562503633297f   // 1/sqrt(17)
#define NSPEC 10

typedef __attribute__((ext_vector_type(8))) short short8;   // 8 bf16
typedef __attribute__((ext_vector_type(4))) float f32x4;    // 4 fp32 acc

#define MFMA16(a, b, c) __builtin_amdgcn_mfma_f32_16x16x32_bf16(a, b, c, 0, 0, 0)

__device__ __forceinline__ short2 cvt2(float a, float b) {
    union { __hip_bfloat162 h; short2 s; } u;
    u.h = __float22bfloat162_rn(make_float2(a, b));
    return u.s;
}
__device__ __forceinline__ short8 cvt8(float4 a, float4 b) {
    short2 p0 = cvt2(a.x, a.y), p1 = cvt2(a.z, a.w);
    short2 p2 = cvt2(b.x, b.y), p3 = cvt2(b.z, b.w);
    short8 r;
    r[0] = p0.x; r[1] = p0.y; r[2] = p1.x; r[3] = p1.y;
    r[4] = p2.x; r[5] = p2.y; r[6] = p3.x; r[7] = p3.y;
    return r;
}
// A-fragment (k-half h) from an fp32 row: elements row[h*32 + q*8 + 0..7]
__device__ __forceinline__ short8 loadArow(const float* rowp, int h, int q) {
    const float* p = rowp + h * 32 + q * 8;
    return cvt8(*(const float4*)p, *(const float4*)(p + 4));
}
// B-fragment from packed bf16 weights (layout built by pack_kernel)
__device__ __forceinline__ short8 loadB(const short* P, int t, int h, int l) {
    return *(const short8*)(P + (((t * 2 + h) * 64 + l) << 3));
}

// ---------------------------------------------------------------------------
// Edge precompute: bessel radial basis w/ envelope, unit vectors Y1 [E,4]
// ---------------------------------------------------------------------------
__global__ __launch_bounds__(256) void edge_pre_kernel(
    const float* __restrict__ vectors, float* __restrict__ rbf, float* __restrict__ Y1)
{
    int e = blockIdx.x * 256 + threadIdx.x;
    float x = vectors[e * 3 + 0], y = vectors[e * 3 + 1], z = vectors[e * 3 + 2];
    float r2 = x * x + y * y + z * z + 1e-12f;
    float r = sqrtf(r2);
    float inv = 1.0f / r;
    *(float4*)(Y1 + e * 4) = make_float4(x * inv, y * inv, z * inv, 0.0f);
    float rc = fmaxf(r, 1e-6f);
    float r6 = r2 * r2 * r2;
    float r7 = r6 * r;
    float r8 = r6 * r2;
    float env = (r < 1.0f) ? (1.0f - 28.0f * r6 + 48.0f * r7 - 21.0f * r8) : 0.0f;
    float sc = 1.41421356237309515f * env / rc;
#pragma unroll
    for (int j = 0; j < 8; ++j)
        rbf[e * 8 + j] = sc * sinf((float)(j + 1) * 3.14159265358979323846f * rc);
}

// ---------------------------------------------------------------------------
// Species counting sort — contention-free, deterministic (ballot/popcount).
// sort1: per-block histograms + stable local ranks
// sort2: block-offset scan (1280 entries)
// sort3: scatter to sidx/rank/spec_srt
// ---------------------------------------------------------------------------
__global__ __launch_bounds__(256) void sort1_kernel(
    const int* __restrict__ species, int* __restrict__ counts_blk,
    int* __restrict__ lrank_arr)
{
    __shared__ int wcnt[4][16];
    int n = blockIdx.x * 256 + threadIdx.x;
    int sp = species[n];
    int lane = threadIdx.x & 63, wv = threadIdx.x >> 6;
    unsigned long long ltmask = (1ull << lane) - 1;
    int lrank_w = 0;
#pragma unroll
    for (int z = 0; z < NSPEC; ++z) {
        unsigned long long m = __ballot(sp == z);
        if (sp == z) lrank_w = __popcll(m & ltmask);
        if (lane == 0) wcnt[wv][z] = __popcll(m);
    }
    __syncthreads();
    int off = 0;
    for (int w = 0; w < wv; ++w) off += wcnt[w][sp];
    lrank_arr[n] = lrank_w + off;
    if (threadIdx.x < NSPEC)
        counts_blk[blockIdx.x * NSPEC + threadIdx.x] =
            wcnt[0][threadIdx.x] + wcnt[1][threadIdx.x] +
            wcnt[2][threadIdx.x] + wcnt[3][threadIdx.x];
}

__global__ __launch_bounds__(64) void sort2_kernel(
    const int* __restrict__ counts_blk, int* __restrict__ off_blk)
{
    __shared__ int total[NSPEC], base[NSPEC];
    int z = threadIdx.x;
    if (z < NSPEC) {
        int t = 0;
        for (int b = 0; b < 128; ++b) t += counts_blk[b * NSPEC + z];
        total[z] = t;
    }
    __syncthreads();
    if (z == 0) {
        int run = 0;
        for (int q = 0; q < NSPEC; ++q) { base[q] = run; run += total[q]; }
    }
    __syncthreads();
    if (z < NSPEC) {
        int run = base[z];
        for (int b = 0; b < 128; ++b) {
            off_blk[b * NSPEC + z] = run;
            run += counts_blk[b * NSPEC + z];
        }
    }
}

__global__ __launch_bounds__(256) void sort3_kernel(
    const int* __restrict__ species, const int* __restrict__ lrank_arr,
    const int* __restrict__ off_blk,
    int* __restrict__ sidx, int* __restrict__ rank, int* __restrict__ spec_srt)
{
    int n = blockIdx.x * 256 + threadIdx.x;
    int sp = species[n];
    int slot = off_blk[blockIdx.x * NSPEC + sp] + lrank_arr[n];
    sidx[slot] = n;
    rank[n] = slot;
    spec_srt[slot] = sp;
}

// ---------------------------------------------------------------------------
// Receiver CSR in SORTED space: histogram over rank[receivers] -> scan ->
// scatter -> per-row insertion sort (determinism + eid locality)
// ---------------------------------------------------------------------------
__global__ __launch_bounds__(256) void hist_kernel(
    const int* __restrict__ receivers, const int* __restrict__ rank,
    int* __restrict__ counts)
{
    int e = blockIdx.x * 256 + threadIdx.x;
    atomicAdd(&counts[rank[receivers[e]]], 1);
}

__global__ __launch_bounds__(1024) void scan_kernel(
    const int* __restrict__ counts, int* __restrict__ row_start, int* __restrict__ cursor)
{
    __shared__ int wave_tot[16];
    int tid = threadIdx.x;
    int c[32];
    int sum = 0;
#pragma unroll
    for (int i = 0; i < 32; ++i) { c[i] = counts[tid * 32 + i]; sum += c[i]; }
    int lane = tid & 63, wv = tid >> 6;
    int x = sum;
#pragma unroll
    for (int off = 1; off < 64; off <<= 1) {
        int y = __shfl_up(x, off);
        if (lane >= off) x += y;
    }
    if (lane == 63) wave_tot[wv] = x;
    __syncthreads();
    if (wv == 0 && lane < 16) {
        int t = wave_tot[lane];
#pragma unroll
        for (int off = 1; off < 16; off <<= 1) {
            int y = __shfl_up(t, off);
            if (lane >= off) t += y;
        }
        wave_tot[lane] = t;
    }
    __syncthreads();
    int excl = x - sum + (wv ? wave_tot[wv - 1] : 0);
    int run = excl;
#pragma unroll
    for (int i = 0; i < 32; ++i) {
        row_start[tid * 32 + i] = run;
        cursor[tid * 32 + i] = run;
        run += c[i];
    }
    if (tid == 1023) row_start[32768] = run;
}

__global__ __launch_bounds__(256) void scatter_kernel(
    const int* __restrict__ receivers, const int* __restrict__ rank,
    int* __restrict__ cursor, int* __restrict__ edge_ids)
{
    int e = blockIdx.x * 256 + threadIdx.x;
    int slot = atomicAdd(&cursor[rank[receivers[e]]], 1);
    edge_ids[slot] = e;
}

__global__ __launch_bounds__(256) void rowsort_kernel(
    const int* __restrict__ row_start, int* __restrict__ edge_ids)
{
    int i = blockIdx.x * 256 + threadIdx.x;
    int beg = row_start[i], end = row_start[i + 1];
    for (int a = beg + 1; a < end; ++a) {
        int key = edge_ids[a];
        int b = a - 1;
        while (b >= beg && edge_ids[b] > key) {
            edge_ids[b + 1] = edge_ids[b];
            --b;
        }
        edge_ids[b + 1] = key;
    }
}

// ranked senders per CSR slot (sorted-space index into s/v)
__global__ __launch_bounds__(256) void sr_kernel(
    const int* __restrict__ senders, const int* __restrict__ edge_ids,
    const int* __restrict__ rank, int* __restrict__ senders_r)
{
    int p = blockIdx.x * 256 + threadIdx.x;
    senders_r[p] = rank[senders[edge_ids[p]]];
}

// ---------------------------------------------------------------------------
// Node init (sorted layout): s[i] = embed_s[spec_srt[i]]
// ---------------------------------------------------------------------------
__global__ __launch_bounds__(256) void init_s_kernel(
    const float* __restrict__ embed_s, const int* __restrict__ spec_srt,
    float* __restrict__ s)
{
    int idx = blockIdx.x * 256 + threadIdx.x;
    s[idx] = embed_s[spec_srt[idx >> 6] * 64 + (idx & 63)];
}

// ---------------------------------------------------------------------------
// Weight pre-pack: 28 64x64 fp32 matrices -> bf16 B-fragment order.
// ---------------------------------------------------------------------------
__global__ __launch_bounds__(256) void pack_kernel(
    const float* __restrict__ Wls, const float* __restrict__ Wlv,
    const float* __restrict__ Wps, const float* __restrict__ Wpv,
    const float* __restrict__ skip_s, const float* __restrict__ skip_v,
    short* __restrict__ packW)
{
    int idx = blockIdx.x * 256 + threadIdx.x;   // 28*4096 = 114688
    if (idx >= 28 * 4096) return;
    int m = idx >> 12, e = idx & 4095;
    int t = e >> 10, h = (e >> 9) & 1, l = (e >> 3) & 63, j = e & 7;
    int fi = h * 32 + ((l >> 4) << 3) + j;
    int fo = t * 16 + (l & 15);
    const float* src;
    if      (m < 2)  src = Wls    + m * 4096;
    else if (m < 4)  src = Wlv    + (m - 2) * 4096;
    else if (m < 6)  src = Wps    + (m - 4) * 4096;
    else if (m < 8)  src = Wpv    + (m - 6) * 4096;
    else if (m < 18) src = skip_s + (m - 8) * 4096;
    else             src = skip_v + (m - 18) * 4096;
    packW[idx] = cvt2(src[fi * 64 + fo], 0.f).x;
}

// ---------------------------------------------------------------------------
// Gather edge kernel (sorted rows, sorted-space CSR): wave owns 4 rows.
// Software pipeline: indices 2-ahead, values 1-ahead — compute waits only on
// loads issued one iteration earlier. Radial weights in VGPRs; no LDS.
// ---------------------------------------------------------------------------
template<int VZERO>
__global__ __launch_bounds__(256) void gather_kernel(
    const float* __restrict__ rbf, const float* __restrict__ Y1,
    const int* __restrict__ edge_ids, const int* __restrict__ senders_r,
    const int* __restrict__ row_start,
    const float* __restrict__ s_in, const float* __restrict__ v_in,
    const float* __restrict__ Wr_i,
    float* __restrict__ agg_s, float* __restrict__ agg_v)
{
    const int wid = threadIdx.x >> 6;
    const int f = threadIdx.x & 63;
    const int base = (blockIdx.x * 4 + wid) * 4;

    float wr[5][8];
#pragma unroll
    for (int j = 0; j < 8; ++j)
#pragma unroll
        for (int p = 0; p < 5; ++p)
            wr[p][j] = Wr_i[j * 320 + p * 64 + f];

    for (int t = 0; t < 4; ++t) {
        int i = base + t;
        int beg = row_start[i], end = row_start[i + 1];
        float a0 = 0.f, a1 = 0.f, a2 = 0.f, a3 = 0.f;
        if (beg < end) {
            int e0 = edge_ids[beg];
            int s0 = senders_r[beg];
            float4 yC  = *(const float4*)(Y1 + (size_t)e0 * 4);
            float4 rAC = *(const float4*)(rbf + (size_t)e0 * 8);
            float4 rBC = *(const float4*)(rbf + (size_t)e0 * 8 + 4);
            float ssC = s_in[(size_t)s0 * 64 + f];
            float v0C = 0.f, v1C = 0.f, v2C = 0.f;
            if (!VZERO) {
                v0C = v_in[((size_t)s0 * 3 + 0) * 64 + f];
                v1C = v_in[((size_t)s0 * 3 + 1) * 64 + f];
                v2C = v_in[((size_t)s0 * 3 + 2) * 64 + f];
            }
            int eN = (beg + 1 < end) ? edge_ids[beg + 1] : e0;
            int sN = (beg + 1 < end) ? senders_r[beg + 1] : s0;
            for (int p = beg; p < end; ++p) {
                // indices for p+2 (sequential, no indirection)
                int e2 = (p + 2 < end) ? edge_ids[p + 2] : eN;
                int s2 = (p + 2 < end) ? senders_r[p + 2] : sN;
                // values for p+1 (eN/sN already resident)
                float4 yNv  = *(const float4*)(Y1 + (size_t)eN * 4);
                float4 rANv = *(const float4*)(rbf + (size_t)eN * 8);
                float4 rBNv = *(const float4*)(rbf + (size_t)eN * 8 + 4);
                float ssN = s_in[(size_t)sN * 64 + f];
                float v0N = 0.f, v1N = 0.f, v2N = 0.f;
                if (!VZERO) {
                    v0N = v_in[((size_t)sN * 3 + 0) * 64 + f];
                    v1N = v_in[((size_t)sN * 3 + 1) * 64 + f];
                    v2N = v_in[((size_t)sN * 3 + 2) * 64 + f];
                }
                // compute with current values
                float rb[8] = {rAC.x, rAC.y, rAC.z, rAC.w, rBC.x, rBC.y, rBC.z, rBC.w};
                float w0 = 0.f, w1 = 0.f, w2 = 0.f, w3 = 0.f, w4 = 0.f;
#pragma unroll
                for (int j = 0; j < 8; ++j) {
                    w0 = fmaf(rb[j], wr[0][j], w0);
                    if (!VZERO) w1 = fmaf(rb[j], wr[1][j], w1);
                    w2 = fmaf(rb[j], wr[2][j], w2);
                    if (!VZERO) w3 = fmaf(rb[j], wr[3][j], w3);
                    if (!VZERO) w4 = fmaf(rb[j], wr[4][j], w4);
                }
                if (VZERO) {
                    a0 += w0 * ssC;
                    float ws2 = w2 * ssC;
                    a1 += ws2 * yC.x; a2 += ws2 * yC.y; a3 += ws2 * yC.z;
                } else {
                    float dot = v0C * yC.x + v1C * yC.y + v2C * yC.z;
                    a0 += w0 * ssC + w1 * dot;
                    float c0 = v1C * yC.z - v2C * yC.y;
                    float c1 = v2C * yC.x - v0C * yC.z;
                    float c2 = v0C * yC.y - v1C * yC.x;
                    float ws2 = w2 * ssC;
                    a1 += ws2 * yC.x + w3 * v0C + w4 * c0;
                    a2 += ws2 * yC.y + w3 * v1C + w4 * c1;
                    a3 += ws2 * yC.z + w3 * v2C + w4 * c2;
                }
                // rotate pipeline
                yC = yNv; rAC = rANv; rBC = rBNv; ssC = ssN;
                v0C = v0N; v1C = v1N; v2C = v2N;
                eN = e2; sN = s2;
            }
        }
        agg_s[(size_t)i * 64 + f] = a0;
        agg_v[((size_t)i * 3 + 0) * 64 + f] = a1;
        agg_v[((size_t)i * 3 + 1) * 64 + f] = a2;
        agg_v[((size_t)i * 3 + 2) * 64 + f] = a3;
    }
}

// ---------------------------------------------------------------------------
// MFMA node kernel (unchanged from R8): wave = 16 sorted nodes.
// ---------------------------------------------------------------------------
__global__ __launch_bounds__(256) void node_mfma_kernel(
    const float* __restrict__ agg_s, const float* __restrict__ agg_v,
    float* s, float* v,
    const short* __restrict__ packW, int it,
    const float* __restrict__ pw_i,
    const int* __restrict__ spec_srt,
    int has_skip)
{
    const int l = threadIdx.x & 63;
    const int wid = threadIdx.x >> 6;
    const int cl = l & 15;
    const int q = l >> 4;
    const int i16 = (blockIdx.x * 4 + wid) * 16;
    __shared__ float xls_all[4][16 * 65];
    float* xls = xls_all[wid];

    const short* pWls = packW + (size_t)(0 + it) * 4096;
    const short* pWlv = packW + (size_t)(2 + it) * 4096;
    const short* pWps = packW + (size_t)(4 + it) * 4096;
    const short* pWpv = packW + (size_t)(6 + it) * 4096;
    const short* pSkS = packW + (size_t)8 * 4096;
    const short* pSkV = packW + (size_t)18 * 4096;
    const short8 z8 = {0, 0, 0, 0, 0, 0, 0, 0};

    const float* ars = agg_s + (size_t)(i16 + cl) * 64;
    short8 As[2] = { loadArow(ars, 0, q), loadArow(ars, 1, q) };
    short8 Av[3][2];
#pragma unroll
    for (int k = 0; k < 3; ++k) {
        const float* r = agg_v + ((size_t)(i16 + cl) * 3 + k) * 64;
        Av[k][0] = loadArow(r, 0, q);
        Av[k][1] = loadArow(r, 1, q);
    }

    f32x4 sD[4];
#pragma unroll
    for (int t = 0; t < 4; ++t) {
        f32x4 acc = {0.f, 0.f, 0.f, 0.f};
        acc = MFMA16(As[0], loadB(pWls, t, 0, l), acc);
        acc = MFMA16(As[1], loadB(pWls, t, 1, l), acc);
        sD[t] = acc;
    }

    f32x4 vD[3][4];
#pragma unroll
    for (int k = 0; k < 3; ++k)
#pragma unroll
        for (int t = 0; t < 4; ++t) vD[k][t] = (f32x4){0.f, 0.f, 0.f, 0.f};
#pragma unroll
    for (int t = 0; t < 4; ++t)
#pragma unroll
        for (int h = 0; h < 2; ++h) {
            short8 b = loadB(pWlv, t, h, l);
#pragma unroll
            for (int k = 0; k < 3; ++k) vD[k][t] = MFMA16(Av[k][h], b, vD[k][t]);
        }

    int z0 = spec_srt[i16], z1 = spec_srt[i16 + 15];
    float psD[4][4], pvsD[4][4];
    if (z0 == z1) {
        const float* pb = pw_i + z0 * 576 + cl;
        float pc[9][4];
#pragma unroll
        for (int c = 0; c < 9; ++c)
#pragma unroll
            for (int t = 0; t < 4; ++t) pc[c][t] = pb[c * 64 + t * 16];
#pragma unroll
        for (int t = 0; t < 4; ++t)
#pragma unroll
            for (int r = 0; r < 4; ++r) {
                float x = sD[t][r] * EPS_C;
                float w0 = vD[0][t][r] * EPS_C;
                float w1 = vD[1][t][r] * EPS_C;
                float w2 = vD[2][t][r] * EPS_C;
                vD[0][t][r] = w0; vD[1][t][r] = w1; vD[2][t][r] = w2;
                float vv = w0 * w0 + w1 * w1 + w2 * w2;
                float x2 = x * x;
                psD[t][r] = pc[0][t] * x + pc[1][t] * x2 + pc[2][t] * vv
                          + pc[3][t] * x2 * x + pc[4][t] * x * vv;
                pvsD[t][r] = pc[5][t] + pc[6][t] * x + pc[7][t] * x2 + pc[8][t] * vv;
            }
    } else {
#pragma unroll
        for (int r = 0; r < 4; ++r) {
            int z = spec_srt[i16 + q * 4 + r];
            const float* pb = pw_i + z * 576 + cl;
#pragma unroll
            for (int t = 0; t < 4; ++t) {
                float p0 = pb[t*16], p1 = pb[64+t*16], p2 = pb[128+t*16];
                float p3 = pb[192+t*16], p4 = pb[256+t*16], p5 = pb[320+t*16];
                float p6 = pb[384+t*16], p7 = pb[448+t*16], p8 = pb[512+t*16];
                float x = sD[t][r] * EPS_C;
                float w0 = vD[0][t][r] * EPS_C;
                float w1 = vD[1][t][r] * EPS_C;
                float w2 = vD[2][t][r] * EPS_C;
                vD[0][t][r] = w0; vD[1][t][r] = w1; vD[2][t][r] = w2;
                float vv = w0 * w0 + w1 * w1 + w2 * w2;
                float x2 = x * x;
                psD[t][r] = p0 * x + p1 * x2 + p2 * vv + p3 * x2 * x + p4 * x * vv;
                pvsD[t][r] = p5 + p6 * x + p7 * x2 + p8 * vv;
            }
        }
    }

#pragma unroll
    for (int t = 0; t < 4; ++t)
#pragma unroll
        for (int r = 0; r < 4; ++r)
            xls[(q * 4 + r) * 65 + t * 16 + cl] = psD[t][r];
    short8 psA[2];
#pragma unroll
    for (int h = 0; h < 2; ++h) {
        const float* rp = xls + cl * 65 + h * 32 + q * 8;
        float t0 = rp[0], t1 = rp[1], t2 = rp[2], t3 = rp[3];
        float t4 = rp[4], t5 = rp[5], t6 = rp[6], t7 = rp[7];
        psA[h] = cvt8(make_float4(t0, t1, t2, t3), make_float4(t4, t5, t6, t7));
    }

    f32x4 snD[4];
#pragma unroll
    for (int t = 0; t < 4; ++t) {
        f32x4 acc = {0.f, 0.f, 0.f, 0.f};
        acc = MFMA16(psA[0], loadB(pWps, t, 0, l), acc);
        acc = MFMA16(psA[1], loadB(pWps, t, 1, l), acc);
        snD[t] = acc;
    }
    if (has_skip) {
        const float* srow = s + (size_t)(i16 + cl) * 64;
        short8 Ai0 = loadArow(srow, 0, q), Ai1 = loadArow(srow, 1, q);
        int myz = spec_srt[i16 + cl];
        for (int z = z0; z <= z1; ++z) {
            bool keep = (myz == z);
            short8 m0 = keep ? Ai0 : z8;
            short8 m1 = keep ? Ai1 : z8;
            const short* pz = pSkS + (size_t)z * 4096;
#pragma unroll
            for (int t = 0; t < 4; ++t) {
                snD[t] = MFMA16(m0, loadB(pz, t, 0, l), snD[t]);
                snD[t] = MFMA16(m1, loadB(pz, t, 1, l), snD[t]);
            }
        }
    }
#pragma unroll
    for (int t = 0; t < 4; ++t)
#pragma unroll
        for (int r = 0; r < 4; ++r)
            s[(size_t)(i16 + q * 4 + r) * 64 + t * 16 + cl] = snD[t][r];

    short8 pvA[3][2];
#pragma unroll
    for (int k = 0; k < 3; ++k) {
#pragma unroll
        for (int t = 0; t < 4; ++t)
#pragma unroll
            for (int r = 0; r < 4; ++r)
                xls[(q * 4 + r) * 65 + t * 16 + cl] = pvsD[t][r] * vD[k][t][r];
#pragma unroll
        for (int h = 0; h < 2; ++h) {
            const float* rp = xls + cl * 65 + h * 32 + q * 8;
            float t0 = rp[0], t1 = rp[1], t2 = rp[2], t3 = rp[3];
            float t4 = rp[4], t5 = rp[5], t6 = rp[6], t7 = rp[7];
            pvA[k][h] = cvt8(make_float4(t0, t1, t2, t3), make_float4(t4, t5, t6, t7));
        }
    }

    f32x4 vnD[3][4];
#pragma unroll
    for (int k = 0; k < 3; ++k)
#pragma unroll
        for (int t = 0; t < 4; ++t) vnD[k][t] = (f32x4){0.f, 0.f, 0.f, 0.f};
#pragma unroll
    for (int t = 0; t < 4; ++t)
#pragma unroll
        for (int h = 0; h < 2; ++h) {
            short8 b = loadB(pWpv, t, h, l);
#pragma unroll
            for (int k = 0; k < 3; ++k) vnD[k][t] = MFMA16(pvA[k][h], b, vnD[k][t]);
        }
    if (has_skip) {
        short8 Aiv[3][2];
#pragma unroll
        for (int k = 0; k < 3; ++k) {
            const float* r = v + ((size_t)(i16 + cl) * 3 + k) * 64;
            Aiv[k][0] = loadArow(r, 0, q);
            Aiv[k][1] = loadArow(r, 1, q);
        }
        int myz = spec_srt[i16 + cl];
        for (int z = z0; z <= z1; ++z) {
            bool keep = (myz == z);
            const short* pz = pSkV + (size_t)z * 4096;
#pragma unroll
            for (int t = 0; t < 4; ++t)
#pragma unroll
                for (int h = 0; h < 2; ++h) {
                    short8 b = loadB(pz, t, h, l);
#pragma unroll
                    for (int k = 0; k < 3; ++k) {
                        short8 a = keep ? Aiv[k][h] : z8;
                        vnD[k][t] = MFMA16(a, b, vnD[k][t]);
                    }
                }
        }
    }
#pragma unroll
    for (int k = 0; k < 3; ++k)
#pragma unroll
        for (int t = 0; t < 4; ++t)
#pragma unroll
            for (int r = 0; r < 4; ++r)
                v[((size_t)(i16 + q * 4 + r) * 3 + k) * 64 + t * 16 + cl] = vnD[k][t][r];
}

// ---------------------------------------------------------------------------
// Readouts (sorted s -> out[sidx])
// ---------------------------------------------------------------------------
__global__ __launch_bounds__(256) void read0_kernel(
    const float* __restrict__ s, const float* __restrict__ Wread0,
    const int* __restrict__ sidx, float* __restrict__ out)
{
    const int wid = threadIdx.x >> 6;
    const int f = threadIdx.x & 63;
    const int i4 = (blockIdx.x * 4 + wid) * 4;
    float w0 = Wread0[f];
#pragma unroll
    for (int t = 0; t < 4; ++t) {
        float a = s[(size_t)(i4 + t) * 64 + f] * w0;
        for (int off = 32; off; off >>= 1) a += __shfl_down(a, off);
        if (f == 0) out[(size_t)sidx[i4 + t] * 2 + 0] = a;
    }
}

__global__ __launch_bounds__(256) void read1_kernel(
    const float* __restrict__ s, const float* __restrict__ Wr1a,
    const float* __restrict__ Wr1b, const int* __restrict__ sidx,
    float* __restrict__ out)
{
    const int wid = threadIdx.x >> 6;
    const int f = threadIdx.x & 63;
    const int i4 = (blockIdx.x * 4 + wid) * 4;
    int hh = f & 15;
    int t0 = f >> 4;
    float a = 0.f;
    const float* sp = s + (size_t)(i4 + t0) * 64;
#pragma unroll 8
    for (int g = 0; g < 64; ++g)
        a = fmaf(sp[g], Wr1a[g * 16 + hh], a);
    float r0 = (a / (1.f + expf(-a))) * Wr1b[hh];
    for (int off = 8; off; off >>= 1) r0 += __shfl_down(r0, off);
    if (hh == 0) out[(size_t)sidx[i4 + t0] * 2 + 1] = r0;
}

// ---------------------------------------------------------------------------
extern "C" void kernel_launch(void* const* d_in, const int* in_sizes, int n_in,
                              void* d_out, int out_size, void* d_ws, size_t ws_size,
                              hipStream_t stream)
{
    const float* vectors = (const float*)d_in[0];
    const float* embed_s = (const float*)d_in[1];
    const float* Wr      = (const float*)d_in[2];   // [2,8,320]
    const float* Wls     = (const float*)d_in[3];   // [2,64,64]
    const float* Wlv     = (const float*)d_in[4];
    const float* skip_s  = (const float*)d_in[5];   // [10,64,64]
    const float* skip_v  = (const float*)d_in[6];
    const float* pw      = (const float*)d_in[7];   // [2,10,9,64]
    const float* Wps     = (const float*)d_in[8];
    const float* Wpv     = (const float*)d_in[9];
    const float* Wread0  = (const float*)d_in[10];  // [64,1]
    const float* Wr1a    = (const float*)d_in[11];  // [64,16]
    const float* Wr1b    = (const float*)d_in[12];  // [16,1]
    const int* senders   = (const int*)d_in[13];
    const int* receivers = (const int*)d_in[14];
    const int* species   = (const int*)d_in[15];
    float* out = (float*)d_out;

    // workspace (sorted-node layout for s/v/agg; CSR in sorted space)
    float* ws = (float*)d_ws;
    float* rbf   = ws; ws += (size_t)N_EDGES * 8;   // 8 MB
    float* Y1    = ws; ws += (size_t)N_EDGES * 4;   // 4 MB
    float* s     = ws; ws += (size_t)N_NODES * 64;  // 8 MB
    float* v     = ws; ws += (size_t)N_NODES * 192; // 24 MB
    float* agg_s = ws; ws += (size_t)N_NODES * 64;  // 8 MB
    float* agg_v = ws; ws += (size_t)N_NODES * 192; // 24 MB
    int* counts    = (int*)ws; ws += N_NODES;
    int* row_start = (int*)ws; ws += N_NODES + 4;
    int* cursor    = (int*)ws; ws += N_NODES;
    int* edge_ids  = (int*)ws; ws += N_EDGES;
    int* senders_r = (int*)ws; ws += N_EDGES;
    int* sidx      = (int*)ws; ws += N_NODES;
    int* rank      = (int*)ws; ws += N_NODES;
    int* spec_srt  = (int*)ws; ws += N_NODES;
    int* lrank_arr = (int*)ws; ws += N_NODES;
    int* counts_blk = (int*)ws; ws += 128 * NSPEC;
    int* off_blk    = (int*)ws; ws += 128 * NSPEC;
    short* packW   = (short*)ws;                    // 28*4096 bf16 = 224 KB

    edge_pre_kernel<<<N_EDGES / 256, 256, 0, stream>>>(vectors, rbf, Y1);

    // species counting sort (no atomics, deterministic)
    sort1_kernel<<<N_NODES / 256, 256, 0, stream>>>(species, counts_blk, lrank_arr);
    sort2_kernel<<<1, 64, 0, stream>>>(counts_blk, off_blk);
    sort3_kernel<<<N_NODES / 256, 256, 0, stream>>>(
        species, lrank_arr, off_blk, sidx, rank, spec_srt);

    // receiver CSR in sorted space + per-row sort + ranked senders
    hipMemsetAsync(counts, 0, N_NODES * sizeof(int), stream);
    hist_kernel<<<N_EDGES / 256, 256, 0, stream>>>(receivers, rank, counts);
    scan_kernel<<<1, 1024, 0, stream>>>(counts, row_start, cursor);
    scatter_kernel<<<N_EDGES / 256, 256, 0, stream>>>(receivers, rank, cursor, edge_ids);
    rowsort_kernel<<<N_NODES / 256, 256, 0, stream>>>(row_start, edge_ids);
    sr_kernel<<<N_EDGES / 256, 256, 0, stream>>>(senders, edge_ids, rank, senders_r);

    init_s_kernel<<<N_NODES * 64 / 256, 256, 0, stream>>>(embed_s, spec_srt, s);
    pack_kernel<<<448, 256, 0, stream>>>(Wls, Wlv, Wps, Wpv, skip_s, skip_v, packW);

    // interaction 0
    gather_kernel<1><<<N_NODES / 16, 256, 0, stream>>>(
        rbf, Y1, edge_ids, senders_r, row_start, s, v, Wr, agg_s, agg_v);
    node_mfma_kernel<<<N_NODES / 64, 256, 0, stream>>>(
        agg_s, agg_v, s, v, packW, 0, pw, spec_srt, 0);
    read0_kernel<<<N_NODES / 16, 256, 0, stream>>>(s, Wread0, sidx, out);

    // interaction 1
    gather_kernel<0><<<N_NODES / 16, 256, 0, stream>>>(
        rbf, Y1, edge_ids, senders_r, row_start, s, v, Wr + 2560, agg_s, agg_v);
    node_mfma_kernel<<<N_NODES / 64, 256, 0, stream>>>(
        agg_s, agg_v, s, v, packW, 1, pw + 5760, spec_srt, 1);
    read1_kernel<<<N_NODES / 16, 256, 0, stream>>>(s, Wr1a, Wr1b, sidx, out);
}